// Round 14
// baseline (303.877 us; speedup 1.0000x reference)
//
#include <hip/hip_runtime.h>

// ---- problem constants (fixed by the reference) ----
#define NN      100000          // nodes (== 6250 * 16)
#define IN_DIM  128
#define HID     32
#define ODIM    64
#define L1C     288             // layer1: 8*32 rel cols + 32 root cols
#define L2K     288             // layer2 K: 8*32 S2 cols + 32 h cols
#define NWGS    392             // scatter workgroups (R14: 196->392, occupancy)
#define NCB     784             // coarse buckets (dst >> 7, 128 nodes each)
#define CCAP    25              // per-(wg,cb) capacity (mean 5.2, +8.7 sigma)
#define RECCAP  2304            // per-cb record LDS buffer (mean 2041, +5.8 sigma)
#define G2ST    296             // LDS g2 tile row stride (288 + 8 pad)
#define PKCAP   512             // per-tile packed LDS stage (mean 256, +16 sigma)

using bf16x8 = __attribute__((ext_vector_type(8))) short;
using f32x4  = __attribute__((ext_vector_type(4))) float;

__device__ __forceinline__ float bf2f(short s) {
    unsigned int u = ((unsigned int)(unsigned short)s) << 16;
    float f; __builtin_memcpy(&f, &u, 4); return f;
}
__device__ __forceinline__ short f2bf(float f) {
    unsigned int u; __builtin_memcpy(&u, &f, 4);
    u += 0x7fffu + ((u >> 16) & 1u);   // RNE
    return (short)(u >> 16);
}
__device__ __forceinline__ float ldf(const void* p, int i, int f32) {
    return f32 ? ((const float*)p)[i] : bf2f(((const short*)p)[i]);
}
__device__ __forceinline__ int ldi(const int* p, long long i, int i64) {
    return i64 ? p[2 * i] : p[(int)i];
}

// ---- per-input dtype detection (1024 thr, independent loads) ----
__global__ __launch_bounds__(1024) void detect(const short* __restrict__ x,
                                               const short* __restrict__ W1,
                                               const short* __restrict__ r1,
                                               const short* __restrict__ W2,
                                               const short* __restrict__ r2,
                                               const short* __restrict__ lw,
                                               const int* __restrict__ ei,
                                               const int* __restrict__ et,
                                               int* __restrict__ flags) {
    __shared__ int cnt[8];
    if (threadIdx.x < 8) cnt[threadIdx.x] = 0;
    __syncthreads();
    const short* ptrs[6] = {x, W1, r1, W2, r2, lw};
    const int    nsmp[6] = {1024, 1024, 1024, 1024, 1024, 64};
    int t = threadIdx.x;
#pragma unroll
    for (int j = 0; j < 6; ++j) {
        if (t < nsmp[j]) {
            unsigned int s = (unsigned short)ptrs[j][2 * t];
            unsigned int e = (s >> 7) & 0xFF;
            if (e >= 140u || (e >= 1u && e <= 100u)) atomicAdd(&cnt[j], 1);
        }
    }
    if (t < 128) {
        if (ei[2 * t + 1] != 0) atomicAdd(&cnt[6], 1);
        if (et[2 * t + 1] != 0) atomicAdd(&cnt[7], 1);
    }
    __syncthreads();
    if (t == 0) {
        const int ns[6] = {1024, 1024, 1024, 1024, 1024, 64};
        for (int j = 0; j < 6; ++j) flags[j] = (cnt[j] * 4 > ns[j]) ? 1 : 0;
        flags[6] = (cnt[6] == 0) ? 1 : 0;
        flags[7] = (cnt[7] == 0) ? 1 : 0;
    }
}

// ---- merged weight prep: w1t (36864) | w2ct (18432) | smallc (256) ----
// Block 0 also zeroes cbTot (cb_sum dispatch deleted; scatter accumulates
// cbTot via device-scope atomics in the NEXT dispatch, stream-ordered).
__global__ __launch_bounds__(256) void prep_all(const void* __restrict__ W1,
                                                const void* __restrict__ root1,
                                                const void* __restrict__ W2,
                                                const void* __restrict__ root2,
                                                const short* __restrict__ b1,
                                                const short* __restrict__ b2,
                                                const void* __restrict__ lin_w,
                                                const short* __restrict__ lin_b,
                                                short* __restrict__ w1t,
                                                short* __restrict__ w2ct,
                                                short* __restrict__ smallc,
                                                int* __restrict__ cbTot,
                                                const int* __restrict__ flags) {
    if (blockIdx.x == 0) {
        for (int j = threadIdx.x; j < NCB; j += 256) cbTot[j] = 0;
    }
    int gi = blockIdx.x * 256 + threadIdx.x;
    if (gi < L1C * IN_DIM) {
        int c = gi >> 7, f = gi & 127;
        float v;
        if (c < 256) { int r = c >> 5, h = c & 31; v = ldf(W1, (r * IN_DIM + f) * HID + h, flags[1]); }
        else         { v = ldf(root1, f * HID + (c - 256), flags[2]); }
        w1t[c * IN_DIM + f] = f2bf(v);
        return;
    }
    int i2 = gi - L1C * IN_DIM;
    if (i2 < ODIM * L2K) {
        int c = i2 / L2K, k = i2 % L2K;
        float v;
        if (k < 256) { int r = k >> 5, kk = k & 31; v = ldf(W2, (r * HID + kk) * ODIM + c, flags[3]); }
        else         { v = ldf(root2, (k - 256) * ODIM + c, flags[4]); }
        w2ct[c * L2K + k] = f2bf(v);
        return;
    }
    int i3 = i2 - ODIM * L2K;
    if (i3 < 256) {
        if (i3 < 32)        smallc[i3] = b1[i3];
        else if (i3 < 96)   smallc[i3] = b2[i3 - 32];
        else if (i3 < 224)  smallc[i3] = f2bf(ldf(lin_w, i3 - 96, flags[5]));
        else if (i3 < 226)  smallc[i3] = lin_b[i3 - 224];
    }
}

// ---- CSR pass 1: WG-private coarse-bucket scatter (1024 thr) ----
// R14: NWGS doubled to 392 (was 0.77 blocks/CU = 38% wave-slot coverage
// with 60 CUs idle; now 1.53 blocks/CU). CCAP 25 (lambda=5.2, P(>=25)
// ~3e-10/cell). Also accumulates cbTot via device-scope atomicAdd.
__global__ __launch_bounds__(1024) void scatter_coarse(const int* __restrict__ ei,
                                                       const int* __restrict__ et,
                                                       int* __restrict__ cnt,
                                                       int* __restrict__ cbTot,
                                                       int* __restrict__ seg, int E,
                                                       const int* __restrict__ flags) {
    __shared__ int cur[NCB];
    if (threadIdx.x < NCB) cur[threadIdx.x] = 0;
    __syncthreads();
    int i64 = flags[6], t64 = flags[7];
    int epw = (E + NWGS - 1) / NWGS;
    int lo = blockIdx.x * epw;
    int hi = lo + epw; if (hi > E) hi = E;
    for (int i = lo + threadIdx.x; i < hi; i += 1024) {
        int s = ldi(ei, i, i64);
        int d = ldi(ei, (long long)E + i, i64);
        int r = ldi(et, i, t64);
        int cb = d >> 7;
        int pos = atomicAdd(&cur[cb], 1);
        if (pos < CCAP)
            seg[(cb * NWGS + (int)blockIdx.x) * CCAP + pos] = ((d & 127) << 20) | (s << 3) | r;
    }
    __syncthreads();
    if (threadIdx.x < NCB) {
        int c = cur[threadIdx.x];
        c = c < CCAP ? c : CCAP;
        cnt[blockIdx.x * NCB + threadIdx.x] = c;
        atomicAdd(&cbTot[threadIdx.x], c);
    }
}

// ---- CSR pass 3: per-cb (128 nodes) LDS sort -> off/inv_deg + packed ----
// Counting-sort key node*8+rel (1024): each node's edge run is REL-SORTED
// (agg2's last-wins partial-sum writes depend on this contiguity).
// R14: WG-scan widened to NWGS=392 via 2-elems-per-thread (same pattern as
// the verified 4-per-thread deg8 scan). packed = (dst&15)<<24 | src<<3 | rel
__global__ __launch_bounds__(256) void build_cb(const int* __restrict__ cnt,
                                                const int* __restrict__ seg,
                                                const int* __restrict__ cbTot,
                                                int* __restrict__ off,
                                                float* __restrict__ inv_deg,
                                                int* __restrict__ packed) {
    __shared__ int cntl[NWGS], soff[NWGS];
    __shared__ int recs[RECCAP];
    __shared__ int deg8[1024], base8[1024], kcur8[1024];
    __shared__ int stmp[256];
    __shared__ int gbase_s;
    int cb = blockIdx.x, tid = threadIdx.x;
    {
        int part = 0;
        for (int j = tid; j < cb; j += 256) part += cbTot[j];
        stmp[tid] = part; __syncthreads();
        for (int o = 128; o > 0; o >>= 1) {
            if (tid < o) stmp[tid] += stmp[tid + o];
            __syncthreads();
        }
        if (tid == 0) gbase_s = stmp[0];
        __syncthreads();
    }
    for (int j = tid; j < NWGS; j += 256) cntl[j] = cnt[j * NCB + cb];
#pragma unroll
    for (int j = 0; j < 4; ++j) { deg8[tid + j * 256] = 0; kcur8[tid + j * 256] = 0; }
    __syncthreads();
    // WG-scan over NWGS=392: 2 elems/thread + 256-wide Hillis-Steele
    int va = (2 * tid < NWGS) ? cntl[2 * tid] : 0;
    int vb = (2 * tid + 1 < NWGS) ? cntl[2 * tid + 1] : 0;
    int vs = va + vb;
    stmp[tid] = vs; __syncthreads();
    for (int o = 1; o < 256; o <<= 1) {
        int u = (tid >= o) ? stmp[tid - o] : 0;
        __syncthreads();
        stmp[tid] += u;
        __syncthreads();
    }
    {
        int excl2 = stmp[tid] - vs;
        if (2 * tid < NWGS)     soff[2 * tid]     = excl2;
        if (2 * tid + 1 < NWGS) soff[2 * tid + 1] = excl2 + va;
    }
    int tot = stmp[255]; if (tot > RECCAP) tot = RECCAP;
    __syncthreads();
    int wave = tid >> 6, lane = tid & 63;
    for (int g = wave; g < NWGS; g += 4) {
        int c = cntl[g], b = soff[g];
        const int* sp = seg + (cb * NWGS + g) * CCAP;
        for (int e = lane; e < c; e += 64)
            if (b + e < RECCAP) recs[b + e] = sp[e];
    }
    __syncthreads();
    for (int i = tid; i < tot; i += 256) {
        int rec = recs[i];
        atomicAdd(&deg8[((rec >> 20) << 3) | (rec & 7)], 1);
    }
    __syncthreads();
    // 1024-key exclusive prefix: 4 keys per thread + 256-scan
    int k0 = tid * 4;
    int d0 = deg8[k0], d1 = deg8[k0 + 1], d2 = deg8[k0 + 2], d3 = deg8[k0 + 3];
    int s01 = d0 + d1, sum4 = s01 + d2 + d3;
    stmp[tid] = sum4; __syncthreads();
    for (int o = 1; o < 256; o <<= 1) {
        int u = (tid >= o) ? stmp[tid - o] : 0;
        __syncthreads();
        stmp[tid] += u;
        __syncthreads();
    }
    int excl = stmp[tid] - sum4;
    base8[k0] = excl; base8[k0 + 1] = excl + d0;
    base8[k0 + 2] = excl + s01; base8[k0 + 3] = excl + s01 + d2;
    __syncthreads();
    int gbase = gbase_s;
    if (tid < 128) {
        int b0 = base8[tid * 8];
        int b1 = (tid < 127) ? base8[(tid + 1) * 8] : tot;
        int dv = b1 - b0;
        int node = cb * 128 + tid;
        if (node <= NN) {
            off[node] = gbase + b0;    // node==NN -> off[NN] = E
            if (node < NN) inv_deg[node] = 1.0f / (float)(dv > 1 ? dv : 1);
        }
    }
    __syncthreads();
    for (int i = tid; i < tot; i += 256) {
        int rec = recs[i];
        int key = ((rec >> 20) << 3) | (rec & 7);
        int p = atomicAdd(&kcur8[key], 1);
        packed[gbase + base8[key] + p] = (((rec >> 20) & 15) << 24) | (rec & 0xFFFFF);
    }
}

// ---- GEMM1: [N,128] x w1t[288,128]^T -> xw [N,288] bf16; 64 rows/wave
__global__ __launch_bounds__(256) void gemm1(const void* __restrict__ x,
                                             const short* __restrict__ w1t,
                                             short* __restrict__ xw,
                                             const int* __restrict__ flags) {
    int wave = threadIdx.x >> 6, lane = threadIdx.x & 63;
    int m = lane & 15, quad = lane >> 4;
    int row0 = (blockIdx.x * 4 + wave) * 64;
    if (row0 >= NN) return;

    bf16x8 a[4][4];
    int fp32 = flags[0];
#pragma unroll
    for (int t = 0; t < 4; ++t) {
        int row = row0 + t * 16 + m;
        int rc = row < NN ? row : NN - 1;
        if (fp32) {
            const float* xr = (const float*)x + rc * IN_DIM + quad * 8;
#pragma unroll
            for (int kt = 0; kt < 4; ++kt) {
                const f32x4* q = (const f32x4*)(xr + kt * 32);
                f32x4 u0 = q[0], u1 = q[1];
                bf16x8 tt;
                tt[0] = f2bf(u0[0]); tt[1] = f2bf(u0[1]); tt[2] = f2bf(u0[2]); tt[3] = f2bf(u0[3]);
                tt[4] = f2bf(u1[0]); tt[5] = f2bf(u1[1]); tt[6] = f2bf(u1[2]); tt[7] = f2bf(u1[3]);
                a[t][kt] = tt;
            }
        } else {
            const short* xr = (const short*)x + rc * IN_DIM + quad * 8;
#pragma unroll
            for (int kt = 0; kt < 4; ++kt) a[t][kt] = *(const bf16x8*)(xr + kt * 32);
        }
    }

    for (int ct = 0; ct < 18; ++ct) {
        const short* wp = w1t + (ct * 16 + m) * IN_DIM + quad * 8;
        bf16x8 b[4];
#pragma unroll
        for (int kt = 0; kt < 4; ++kt) b[kt] = *(const bf16x8*)(wp + kt * 32);
#pragma unroll
        for (int t = 0; t < 4; ++t) {
            f32x4 acc = {0.f, 0.f, 0.f, 0.f};
#pragma unroll
            for (int kt = 0; kt < 4; ++kt)
                acc = __builtin_amdgcn_mfma_f32_16x16x32_bf16(a[t][kt], b[kt], acc, 0, 0, 0);
#pragma unroll
            for (int i = 0; i < 4; ++i) {
                int r = row0 + t * 16 + quad * 4 + i;
                if (r < NN) xw[r * L1C + ct * 16 + m] = f2bf(acc[i]);
            }
        }
    }
}

// ---- layer-1 aggregation (R11, mirrors agg2's proven gather engine):
// 16 nodes/block, 16 lanes/node x 2 dims/lane (unsigned 2xbf16 gathers),
// packed staged to LDS once per block, batch-8 gathers in flight,
// vectorized root/bias/h I/O. ReLU'd bf16 out.
__global__ __launch_bounds__(256) void agg1(const short* __restrict__ xw,
                                            const int* __restrict__ off,
                                            const int* __restrict__ packed,
                                            const float* __restrict__ inv_deg,
                                            const short* __restrict__ smallc,
                                            short* __restrict__ h) {
    __shared__ int pk_l[PKCAP];                        // 2 KB
    __shared__ float invl[16];
    int tid = threadIdx.x;
    int row0 = blockIdx.x * 16;                        // NN % 16 == 0
    if (tid < 16) invl[tid] = inv_deg[row0 + tid];
    int st = off[row0];
    int tot = off[row0 + 16] - st;
    for (int j = tid; j < tot && j < PKCAP; j += 256) pk_l[j] = packed[st + j];
    __syncthreads();

    int node = tid >> 4, l = tid & 15;                 // 16 lanes/node, 2 dims/lane
    int s = off[row0 + node] - st, en = off[row0 + node + 1] - st;
    const short* xp = xw + l * 2;                      // + src*L1C + rel*32 (4B-aligned)
    float a0 = 0.f, a1 = 0.f;

    auto ldpk = [&](int j) -> int {
        return (j < PKCAP) ? pk_l[j] : packed[st + j];
    };
    auto gv = [&](int pk) -> unsigned {
        return *(const unsigned*)(xp + ((pk >> 3) & 0x1FFFF) * L1C + (pk & 7) * 32);
    };

    int i = s;
    for (; i + 7 < en; i += 8) {                       // batch-8: 8 gathers in flight
        int p0 = ldpk(i),     p1 = ldpk(i + 1), p2 = ldpk(i + 2), p3 = ldpk(i + 3);
        int p4 = ldpk(i + 4), p5 = ldpk(i + 5), p6 = ldpk(i + 6), p7 = ldpk(i + 7);
        unsigned v0 = gv(p0), v1 = gv(p1), v2 = gv(p2), v3 = gv(p3);
        unsigned v4 = gv(p4), v5 = gv(p5), v6 = gv(p6), v7 = gv(p7);
        a0 += ((bf2f((short)(v0 & 0xFFFF)) + bf2f((short)(v1 & 0xFFFF)))
             + (bf2f((short)(v2 & 0xFFFF)) + bf2f((short)(v3 & 0xFFFF))))
            + ((bf2f((short)(v4 & 0xFFFF)) + bf2f((short)(v5 & 0xFFFF)))
             + (bf2f((short)(v6 & 0xFFFF)) + bf2f((short)(v7 & 0xFFFF))));
        a1 += ((bf2f((short)(v0 >> 16)) + bf2f((short)(v1 >> 16)))
             + (bf2f((short)(v2 >> 16)) + bf2f((short)(v3 >> 16))))
            + ((bf2f((short)(v4 >> 16)) + bf2f((short)(v5 >> 16)))
             + (bf2f((short)(v6 >> 16)) + bf2f((short)(v7 >> 16))));
    }
    for (; i + 3 < en; i += 4) {
        int p0 = ldpk(i), p1 = ldpk(i + 1), p2 = ldpk(i + 2), p3 = ldpk(i + 3);
        unsigned v0 = gv(p0), v1 = gv(p1), v2 = gv(p2), v3 = gv(p3);
        a0 += (bf2f((short)(v0 & 0xFFFF)) + bf2f((short)(v1 & 0xFFFF)))
            + (bf2f((short)(v2 & 0xFFFF)) + bf2f((short)(v3 & 0xFFFF)));
        a1 += (bf2f((short)(v0 >> 16)) + bf2f((short)(v1 >> 16)))
            + (bf2f((short)(v2 >> 16)) + bf2f((short)(v3 >> 16)));
    }
    for (; i < en; ++i) {
        unsigned v = gv(ldpk(i));
        a0 += bf2f((short)(v & 0xFFFF));
        a1 += bf2f((short)(v >> 16));
    }

    float inv = invl[node];
    unsigned rt = *(const unsigned*)(xw + (row0 + node) * L1C + 256 + l * 2);
    unsigned bc = *(const unsigned*)(smallc + l * 2);
    float o0 = a0 * inv + bf2f((short)(rt & 0xFFFF)) + bf2f((short)(bc & 0xFFFF));
    float o1 = a1 * inv + bf2f((short)(rt >> 16)) + bf2f((short)(bc >> 16));
    o0 = o0 > 0.f ? o0 : 0.f;
    o1 = o1 > 0.f ? o1 : 0.f;
    unsigned w = ((unsigned)(unsigned short)f2bf(o1) << 16) | (unsigned short)f2bf(o0);
    *(unsigned*)(h + (row0 + node) * HID + l * 2) = w;
}

// ---- fused layer-2 (R7, at structural floor): flat batch-8 gather +
// branchless last-wins LDS partial-sum writes (edges rel-sorted per node).
__global__ __launch_bounds__(256) void agg2_fused(const short* __restrict__ h,
                                                  const int* __restrict__ off,
                                                  const int* __restrict__ packed,
                                                  const float* __restrict__ inv_deg,
                                                  const short* __restrict__ w2ct,
                                                  const short* __restrict__ smallc,
                                                  float* __restrict__ out) {
    __shared__ __align__(16) short g2l[16 * G2ST];     // 9.25 KB
    __shared__ int pk_l[PKCAP];                        // 2 KB
    __shared__ float red[4][16][2];
    __shared__ float invl[16];
    int tid = threadIdx.x;
    int row0 = blockIdx.x * 16;                        // NN % 16 == 0
    if (tid < 16) invl[tid] = inv_deg[row0 + tid];
    int st = off[row0];
    int tot = off[row0 + 16] - st;
    // zero the tile (empty (node,rel) cells must be 0) + stage packed
    {
        unsigned* gz = (unsigned*)g2l;
        const int nu = 16 * G2ST / 2;                  // 2368 uints
        for (int j = tid; j < nu; j += 256) gz[j] = 0;
        for (int j = tid; j < tot && j < PKCAP; j += 256) pk_l[j] = packed[st + j];
    }
    __syncthreads();

    int node = tid >> 4, l = tid & 15;                 // 16 lanes/node, 2 dims/lane
    int s = off[row0 + node] - st, en = off[row0 + node + 1] - st;
    float inv = invl[node];
    const short* hp = h + l * 2;
    short* grow = g2l + node * G2ST + l * 2;
    float a0 = 0.f, a1 = 0.f;
    int cur = -1;

    auto ldpk = [&](int j) -> int {
        return (j < PKCAP) ? pk_l[j] : packed[st + j];
    };
    // branchless accumulate + last-wins partial store (v_cndmask, no branch)
    auto acc_edge = [&](int pk, unsigned hv) {
        int rel = pk & 7;
        bool nr = (rel != cur);
        float lo = bf2f((short)(hv & 0xFFFF)) * inv;
        float hi = bf2f((short)(hv >> 16)) * inv;
        a0 = (nr ? 0.f : a0) + lo;
        a1 = (nr ? 0.f : a1) + hi;
        cur = rel;
        unsigned w = ((unsigned)(unsigned short)f2bf(a1) << 16)
                   | (unsigned short)f2bf(a0);
        *(unsigned*)(grow + rel * 32) = w;             // last write per rel wins
    };

    int i = s;
    for (; i + 7 < en; i += 8) {                       // batch-8: 8 gathers in flight
        int p0 = ldpk(i),     p1 = ldpk(i + 1), p2 = ldpk(i + 2), p3 = ldpk(i + 3);
        int p4 = ldpk(i + 4), p5 = ldpk(i + 5), p6 = ldpk(i + 6), p7 = ldpk(i + 7);
        unsigned v0 = *(const unsigned*)(hp + ((p0 >> 3) & 0x1FFFF) * HID);
        unsigned v1 = *(const unsigned*)(hp + ((p1 >> 3) & 0x1FFFF) * HID);
        unsigned v2 = *(const unsigned*)(hp + ((p2 >> 3) & 0x1FFFF) * HID);
        unsigned v3 = *(const unsigned*)(hp + ((p3 >> 3) & 0x1FFFF) * HID);
        unsigned v4 = *(const unsigned*)(hp + ((p4 >> 3) & 0x1FFFF) * HID);
        unsigned v5 = *(const unsigned*)(hp + ((p5 >> 3) & 0x1FFFF) * HID);
        unsigned v6 = *(const unsigned*)(hp + ((p6 >> 3) & 0x1FFFF) * HID);
        unsigned v7 = *(const unsigned*)(hp + ((p7 >> 3) & 0x1FFFF) * HID);
        acc_edge(p0, v0); acc_edge(p1, v1); acc_edge(p2, v2); acc_edge(p3, v3);
        acc_edge(p4, v4); acc_edge(p5, v5); acc_edge(p6, v6); acc_edge(p7, v7);
    }
    for (; i + 3 < en; i += 4) {
        int p0 = ldpk(i), p1 = ldpk(i + 1), p2 = ldpk(i + 2), p3 = ldpk(i + 3);
        unsigned v0 = *(const unsigned*)(hp + ((p0 >> 3) & 0x1FFFF) * HID);
        unsigned v1 = *(const unsigned*)(hp + ((p1 >> 3) & 0x1FFFF) * HID);
        unsigned v2 = *(const unsigned*)(hp + ((p2 >> 3) & 0x1FFFF) * HID);
        unsigned v3 = *(const unsigned*)(hp + ((p3 >> 3) & 0x1FFFF) * HID);
        acc_edge(p0, v0); acc_edge(p1, v1); acc_edge(p2, v2); acc_edge(p3, v3);
    }
    for (; i < en; ++i) {
        int p = ldpk(i);
        unsigned v = *(const unsigned*)(hp + ((p >> 3) & 0x1FFFF) * HID);
        acc_edge(p, v);
    }

    // root cols 256..287 (unscaled h of the node itself)
    *(unsigned*)(grow + 256) = *(const unsigned*)(h + (row0 + node) * HID + l * 2);
    __syncthreads();

    // phase B: 4 waves, wave = 16-col block; MFMA over K=288 from LDS
    int wave = tid >> 6, lane = tid & 63;
    int m15 = lane & 15, quad = lane >> 4;
    const short* wp = w2ct + (wave * 16 + m15) * L2K + quad * 8;
    bf16x8 a[9], b[9];
#pragma unroll
    for (int kt = 0; kt < 9; ++kt) {
        b[kt] = *(const bf16x8*)(wp + kt * 32);
        a[kt] = *(const bf16x8*)(&g2l[m15 * G2ST + quad * 8 + kt * 32]);
    }
    f32x4 acc = {0.f, 0.f, 0.f, 0.f};
#pragma unroll
    for (int kt = 0; kt < 9; ++kt)
        acc = __builtin_amdgcn_mfma_f32_16x16x32_bf16(a[kt], b[kt], acc, 0, 0, 0);

    int c = wave * 16 + m15;
    float lw0 = bf2f(smallc[96 + c * 2 + 0]);
    float lw1 = bf2f(smallc[96 + c * 2 + 1]);
    float b2c = bf2f(smallc[32 + c]);
    float pr0[4], pr1[4];
#pragma unroll
    for (int i2 = 0; i2 < 4; ++i2) {
        float v = acc[i2] + b2c;
        pr0[i2] = v * lw0;
        pr1[i2] = v * lw1;
    }
#pragma unroll
    for (int o = 1; o < 16; o <<= 1) {
#pragma unroll
        for (int i2 = 0; i2 < 4; ++i2) {
            pr0[i2] += __shfl_xor(pr0[i2], o, 64);
            pr1[i2] += __shfl_xor(pr1[i2], o, 64);
        }
    }
    if (m15 == 0) {
#pragma unroll
        for (int i2 = 0; i2 < 4; ++i2) {
            red[wave][quad * 4 + i2][0] = pr0[i2];
            red[wave][quad * 4 + i2][1] = pr1[i2];
        }
    }
    __syncthreads();
    if (tid < 32) {
        int row = tid >> 1, j = tid & 1;
        float v = red[0][row][j] + red[1][row][j] + red[2][row][j] + red[3][row][j]
                + bf2f(smallc[224 + j]);
        out[(row0 + row) * 2 + j] = v;
    }
}

extern "C" void kernel_launch(void* const* d_in, const int* in_sizes, int n_in,
                              void* d_out, int out_size, void* d_ws, size_t ws_size,
                              hipStream_t stream) {
    const void* x     = d_in[0];
    const int*  ei    = (const int*)d_in[1];
    const int*  etype = (const int*)d_in[2];
    const void* W1    = d_in[3];
    const void* root1 = d_in[4];
    const void* b1    = d_in[5];
    const void* W2    = d_in[6];
    const void* root2 = d_in[7];
    const void* b2    = d_in[8];
    const void* lin_w = d_in[9];
    const void* lin_b = d_in[10];
    float* out = (float*)d_out;          // fp32 output (verified round 4)

    const int E = in_sizes[2];          // 1,600,000

    // workspace carve (256B aligned). Peak ~103 MB.
    char* p = (char*)d_ws;
    auto alloc = [&](size_t bytes) { char* r = p; p += (bytes + 255) & ~(size_t)255; return (void*)r; };
    int*   flags   = (int*)  alloc(256);
    int*   off     = (int*)  alloc((size_t)(NN + 1) * 4);
    float* inv_deg = (float*)alloc((size_t)NN * 4);
    int*   packed  = (int*)  alloc((size_t)E * 4);
    int*   cnt     = (int*)  alloc((size_t)NWGS * NCB * 4);
    int*   cbTot   = (int*)  alloc((size_t)NCB * 4);
    int*   seg     = (int*)  alloc((size_t)NCB * NWGS * CCAP * 4);   // 30.7 MB
    short* w1t     = (short*)alloc((size_t)L1C * IN_DIM * 2);
    short* w2ct    = (short*)alloc((size_t)ODIM * L2K * 2);
    short* smallc  = (short*)alloc(256 * 2);
    short* h       = (short*)alloc((size_t)NN * HID * 2);
    short* xw1     = (short*)alloc((size_t)NN * L1C * 2);            // 57.6 MB

    detect<<<1, 1024, 0, stream>>>((const short*)x, (const short*)W1, (const short*)root1,
                                   (const short*)W2, (const short*)root2, (const short*)lin_w,
                                   ei, etype, flags);
    const int prep_items = L1C * IN_DIM + ODIM * L2K + 256;
    prep_all<<<(prep_items + 255) / 256, 256, 0, stream>>>(W1, root1, W2, root2,
                                                           (const short*)b1, (const short*)b2,
                                                           lin_w, (const short*)lin_b,
                                                           w1t, w2ct, smallc, cbTot, flags);

    scatter_coarse<<<NWGS, 1024, 0, stream>>>(ei, etype, cnt, cbTot, seg, E, flags);
    build_cb<<<NCB, 256, 0, stream>>>(cnt, seg, cbTot, off, inv_deg, packed);

    gemm1<<<((NN + 63) / 64 + 3) / 4, 256, 0, stream>>>(x, w1t, xw1, flags);
    agg1<<<NN / 16, 256, 0, stream>>>(xw1, off, packed, inv_deg, smallc, h);
    agg2_fused<<<NN / 16, 256, 0, stream>>>(h, off, packed, inv_deg, w2ct, smallc, out);
}

// Round 15
// 265.398 us; speedup vs baseline: 1.1450x; 1.1450x over previous
//
#include <hip/hip_runtime.h>

// ---- problem constants (fixed by the reference) ----
#define NN      100000          // nodes (== 6250 * 16)
#define IN_DIM  128
#define HID     32
#define ODIM    64
#define L1C     288             // layer1: 8*32 rel cols + 32 root cols
#define L2K     288             // layer2 K: 8*32 S2 cols + 32 h cols
#define NWGS    196             // scatter workgroups (R15: reverted, scatter exonerated)
#define NCB     784             // coarse buckets (dst >> 7, 128 nodes each)
#define CCAP    40              // per-(wg,cb) capacity (mean 10.4)
#define RECCAP  2304            // per-cb record LDS buffer (mean 2041, +5.8 sigma)
#define G2ST    296             // LDS g2 tile row stride (288 + 8 pad)
#define PKCAP   512             // per-tile packed LDS stage (mean 256, +16 sigma)

using bf16x8 = __attribute__((ext_vector_type(8))) short;
using f32x4  = __attribute__((ext_vector_type(4))) float;

__device__ __forceinline__ float bf2f(short s) {
    unsigned int u = ((unsigned int)(unsigned short)s) << 16;
    float f; __builtin_memcpy(&f, &u, 4); return f;
}
__device__ __forceinline__ short f2bf(float f) {
    unsigned int u; __builtin_memcpy(&u, &f, 4);
    u += 0x7fffu + ((u >> 16) & 1u);   // RNE
    return (short)(u >> 16);
}
__device__ __forceinline__ float ldf(const void* p, int i, int f32) {
    return f32 ? ((const float*)p)[i] : bf2f(((const short*)p)[i]);
}
__device__ __forceinline__ int ldi(const int* p, long long i, int i64) {
    return i64 ? p[2 * i] : p[(int)i];
}

// ---- per-input dtype detection (1024 thr, independent loads) ----
__global__ __launch_bounds__(1024) void detect(const short* __restrict__ x,
                                               const short* __restrict__ W1,
                                               const short* __restrict__ r1,
                                               const short* __restrict__ W2,
                                               const short* __restrict__ r2,
                                               const short* __restrict__ lw,
                                               const int* __restrict__ ei,
                                               const int* __restrict__ et,
                                               int* __restrict__ flags) {
    __shared__ int cnt[8];
    if (threadIdx.x < 8) cnt[threadIdx.x] = 0;
    __syncthreads();
    const short* ptrs[6] = {x, W1, r1, W2, r2, lw};
    const int    nsmp[6] = {1024, 1024, 1024, 1024, 1024, 64};
    int t = threadIdx.x;
#pragma unroll
    for (int j = 0; j < 6; ++j) {
        if (t < nsmp[j]) {
            unsigned int s = (unsigned short)ptrs[j][2 * t];
            unsigned int e = (s >> 7) & 0xFF;
            if (e >= 140u || (e >= 1u && e <= 100u)) atomicAdd(&cnt[j], 1);
        }
    }
    if (t < 128) {
        if (ei[2 * t + 1] != 0) atomicAdd(&cnt[6], 1);
        if (et[2 * t + 1] != 0) atomicAdd(&cnt[7], 1);
    }
    __syncthreads();
    if (t == 0) {
        const int ns[6] = {1024, 1024, 1024, 1024, 1024, 64};
        for (int j = 0; j < 6; ++j) flags[j] = (cnt[j] * 4 > ns[j]) ? 1 : 0;
        flags[6] = (cnt[6] == 0) ? 1 : 0;
        flags[7] = (cnt[7] == 0) ? 1 : 0;
    }
}

// ---- merged weight prep: w1t (36864) | w2ct (18432) | smallc (256) ----
// Block 0 also zeroes cbTot (cb_sum dispatch deleted; scatter accumulates
// cbTot via device-scope atomics in the NEXT dispatch, stream-ordered).
__global__ __launch_bounds__(256) void prep_all(const void* __restrict__ W1,
                                                const void* __restrict__ root1,
                                                const void* __restrict__ W2,
                                                const void* __restrict__ root2,
                                                const short* __restrict__ b1,
                                                const short* __restrict__ b2,
                                                const void* __restrict__ lin_w,
                                                const short* __restrict__ lin_b,
                                                short* __restrict__ w1t,
                                                short* __restrict__ w2ct,
                                                short* __restrict__ smallc,
                                                int* __restrict__ cbTot,
                                                const int* __restrict__ flags) {
    if (blockIdx.x == 0) {
        for (int j = threadIdx.x; j < NCB; j += 256) cbTot[j] = 0;
    }
    int gi = blockIdx.x * 256 + threadIdx.x;
    if (gi < L1C * IN_DIM) {
        int c = gi >> 7, f = gi & 127;
        float v;
        if (c < 256) { int r = c >> 5, h = c & 31; v = ldf(W1, (r * IN_DIM + f) * HID + h, flags[1]); }
        else         { v = ldf(root1, f * HID + (c - 256), flags[2]); }
        w1t[c * IN_DIM + f] = f2bf(v);
        return;
    }
    int i2 = gi - L1C * IN_DIM;
    if (i2 < ODIM * L2K) {
        int c = i2 / L2K, k = i2 % L2K;
        float v;
        if (k < 256) { int r = k >> 5, kk = k & 31; v = ldf(W2, (r * HID + kk) * ODIM + c, flags[3]); }
        else         { v = ldf(root2, (k - 256) * ODIM + c, flags[4]); }
        w2ct[c * L2K + k] = f2bf(v);
        return;
    }
    int i3 = i2 - ODIM * L2K;
    if (i3 < 256) {
        if (i3 < 32)        smallc[i3] = b1[i3];
        else if (i3 < 96)   smallc[i3] = b2[i3 - 32];
        else if (i3 < 224)  smallc[i3] = f2bf(ldf(lin_w, i3 - 96, flags[5]));
        else if (i3 < 226)  smallc[i3] = lin_b[i3 - 224];
    }
}

// ---- CSR pass 1: WG-private coarse-bucket scatter (1024 thr) ----
// Also accumulates per-cb totals into cbTot via device-scope atomicAdd.
__global__ __launch_bounds__(1024) void scatter_coarse(const int* __restrict__ ei,
                                                       const int* __restrict__ et,
                                                       int* __restrict__ cnt,
                                                       int* __restrict__ cbTot,
                                                       int* __restrict__ seg, int E,
                                                       const int* __restrict__ flags) {
    __shared__ int cur[NCB];
    if (threadIdx.x < NCB) cur[threadIdx.x] = 0;
    __syncthreads();
    int i64 = flags[6], t64 = flags[7];
    int epw = (E + NWGS - 1) / NWGS;
    int lo = blockIdx.x * epw;
    int hi = lo + epw; if (hi > E) hi = E;
    for (int i = lo + threadIdx.x; i < hi; i += 1024) {
        int s = ldi(ei, i, i64);
        int d = ldi(ei, (long long)E + i, i64);
        int r = ldi(et, i, t64);
        int cb = d >> 7;
        int pos = atomicAdd(&cur[cb], 1);
        if (pos < CCAP)
            seg[(cb * NWGS + (int)blockIdx.x) * CCAP + pos] = ((d & 127) << 20) | (s << 3) | r;
    }
    __syncthreads();
    if (threadIdx.x < NCB) {
        int c = cur[threadIdx.x];
        c = c < CCAP ? c : CCAP;
        cnt[blockIdx.x * NCB + threadIdx.x] = c;
        atomicAdd(&cbTot[threadIdx.x], c);
    }
}

// ---- CSR pass 3 (R15 restructure): 512 threads (2x resident waves at the
// same 784-block grid: latency-bound phases, occupancy was 27%) + FLAT
// slot-space seg->recs copy (j over NWGS*CCAP, coalesced, independent —
// replaces the group-serial per-wave loop that scaled with NWGS).
// Counting-sort key node*8+rel (1024): runs stay REL-SORTED per node.
// packed = (dst&15)<<24 | src<<3 | rel
__global__ __launch_bounds__(512) void build_cb(const int* __restrict__ cnt,
                                                const int* __restrict__ seg,
                                                const int* __restrict__ cbTot,
                                                int* __restrict__ off,
                                                float* __restrict__ inv_deg,
                                                int* __restrict__ packed) {
    __shared__ int cntl[NWGS], soff[NWGS];
    __shared__ int recs[RECCAP];
    __shared__ int deg8[1024], base8[1024], kcur8[1024];
    __shared__ int stmp[512];
    __shared__ int gbase_s;
    int cb = blockIdx.x, tid = threadIdx.x;
    {
        int part = 0;
        for (int j = tid; j < cb; j += 512) part += cbTot[j];
        stmp[tid] = part; __syncthreads();
        for (int o = 256; o > 0; o >>= 1) {
            if (tid < o) stmp[tid] += stmp[tid + o];
            __syncthreads();
        }
        if (tid == 0) gbase_s = stmp[0];
        __syncthreads();
    }
    if (tid < NWGS) cntl[tid] = cnt[tid * NCB + cb];
    for (int j = tid; j < 1024; j += 512) { deg8[j] = 0; kcur8[j] = 0; }
    __syncthreads();
    // 512-wide inclusive scan over NWGS counts (entries >=NWGS are 0)
    int v = (tid < NWGS) ? cntl[tid] : 0;
    stmp[tid] = v; __syncthreads();
    for (int o = 1; o < 512; o <<= 1) {
        int u = (tid >= o) ? stmp[tid - o] : 0;
        __syncthreads();
        stmp[tid] += u;
        __syncthreads();
    }
    if (tid < NWGS) soff[tid] = stmp[tid] - v;
    int tot = stmp[511]; if (tot > RECCAP) tot = RECCAP;
    __syncthreads();
    // flat slot-space copy: coalesced seg reads, no serial group chain
    {
        const int* segp = seg + (size_t)cb * NWGS * CCAP;
        for (int j = tid; j < NWGS * CCAP; j += 512) {
            int g = j / CCAP, e = j - g * CCAP;
            if (e < cntl[g]) {
                int b = soff[g] + e;
                if (b < RECCAP) recs[b] = segp[j];
            }
        }
    }
    __syncthreads();
    for (int i = tid; i < tot; i += 512) {
        int rec = recs[i];
        atomicAdd(&deg8[((rec >> 20) << 3) | (rec & 7)], 1);
    }
    __syncthreads();
    // 1024-key exclusive prefix: 2 keys per thread + 512-scan
    int k0 = tid * 2;
    int d0 = deg8[k0], d1 = deg8[k0 + 1];
    int sum2 = d0 + d1;
    stmp[tid] = sum2; __syncthreads();
    for (int o = 1; o < 512; o <<= 1) {
        int u = (tid >= o) ? stmp[tid - o] : 0;
        __syncthreads();
        stmp[tid] += u;
        __syncthreads();
    }
    int excl = stmp[tid] - sum2;
    base8[k0] = excl; base8[k0 + 1] = excl + d0;
    __syncthreads();
    int gbase = gbase_s;
    if (tid < 128) {
        int b0 = base8[tid * 8];
        int b1 = (tid < 127) ? base8[(tid + 1) * 8] : tot;
        int dv = b1 - b0;
        int node = cb * 128 + tid;
        if (node <= NN) {
            off[node] = gbase + b0;    // node==NN -> off[NN] = E
            if (node < NN) inv_deg[node] = 1.0f / (float)(dv > 1 ? dv : 1);
        }
    }
    __syncthreads();
    for (int i = tid; i < tot; i += 512) {
        int rec = recs[i];
        int key = ((rec >> 20) << 3) | (rec & 7);
        int p = atomicAdd(&kcur8[key], 1);
        packed[gbase + base8[key] + p] = (((rec >> 20) & 15) << 24) | (rec & 0xFFFFF);
    }
}

// ---- GEMM1: [N,128] x w1t[288,128]^T -> xw [N,288] bf16; 64 rows/wave
__global__ __launch_bounds__(256) void gemm1(const void* __restrict__ x,
                                             const short* __restrict__ w1t,
                                             short* __restrict__ xw,
                                             const int* __restrict__ flags) {
    int wave = threadIdx.x >> 6, lane = threadIdx.x & 63;
    int m = lane & 15, quad = lane >> 4;
    int row0 = (blockIdx.x * 4 + wave) * 64;
    if (row0 >= NN) return;

    bf16x8 a[4][4];
    int fp32 = flags[0];
#pragma unroll
    for (int t = 0; t < 4; ++t) {
        int row = row0 + t * 16 + m;
        int rc = row < NN ? row : NN - 1;
        if (fp32) {
            const float* xr = (const float*)x + rc * IN_DIM + quad * 8;
#pragma unroll
            for (int kt = 0; kt < 4; ++kt) {
                const f32x4* q = (const f32x4*)(xr + kt * 32);
                f32x4 u0 = q[0], u1 = q[1];
                bf16x8 tt;
                tt[0] = f2bf(u0[0]); tt[1] = f2bf(u0[1]); tt[2] = f2bf(u0[2]); tt[3] = f2bf(u0[3]);
                tt[4] = f2bf(u1[0]); tt[5] = f2bf(u1[1]); tt[6] = f2bf(u1[2]); tt[7] = f2bf(u1[3]);
                a[t][kt] = tt;
            }
        } else {
            const short* xr = (const short*)x + rc * IN_DIM + quad * 8;
#pragma unroll
            for (int kt = 0; kt < 4; ++kt) a[t][kt] = *(const bf16x8*)(xr + kt * 32);
        }
    }

    for (int ct = 0; ct < 18; ++ct) {
        const short* wp = w1t + (ct * 16 + m) * IN_DIM + quad * 8;
        bf16x8 b[4];
#pragma unroll
        for (int kt = 0; kt < 4; ++kt) b[kt] = *(const bf16x8*)(wp + kt * 32);
#pragma unroll
        for (int t = 0; t < 4; ++t) {
            f32x4 acc = {0.f, 0.f, 0.f, 0.f};
#pragma unroll
            for (int kt = 0; kt < 4; ++kt)
                acc = __builtin_amdgcn_mfma_f32_16x16x32_bf16(a[t][kt], b[kt], acc, 0, 0, 0);
#pragma unroll
            for (int i = 0; i < 4; ++i) {
                int r = row0 + t * 16 + quad * 4 + i;
                if (r < NN) xw[r * L1C + ct * 16 + m] = f2bf(acc[i]);
            }
        }
    }
}

// ---- layer-1 aggregation (R11, mirrors agg2's proven gather engine):
// 16 nodes/block, 16 lanes/node x 2 dims/lane (unsigned 2xbf16 gathers),
// packed staged to LDS once per block, batch-8 gathers in flight,
// vectorized root/bias/h I/O. ReLU'd bf16 out.
__global__ __launch_bounds__(256) void agg1(const short* __restrict__ xw,
                                            const int* __restrict__ off,
                                            const int* __restrict__ packed,
                                            const float* __restrict__ inv_deg,
                                            const short* __restrict__ smallc,
                                            short* __restrict__ h) {
    __shared__ int pk_l[PKCAP];                        // 2 KB
    __shared__ float invl[16];
    int tid = threadIdx.x;
    int row0 = blockIdx.x * 16;                        // NN % 16 == 0
    if (tid < 16) invl[tid] = inv_deg[row0 + tid];
    int st = off[row0];
    int tot = off[row0 + 16] - st;
    for (int j = tid; j < tot && j < PKCAP; j += 256) pk_l[j] = packed[st + j];
    __syncthreads();

    int node = tid >> 4, l = tid & 15;                 // 16 lanes/node, 2 dims/lane
    int s = off[row0 + node] - st, en = off[row0 + node + 1] - st;
    const short* xp = xw + l * 2;                      // + src*L1C + rel*32 (4B-aligned)
    float a0 = 0.f, a1 = 0.f;

    auto ldpk = [&](int j) -> int {
        return (j < PKCAP) ? pk_l[j] : packed[st + j];
    };
    auto gv = [&](int pk) -> unsigned {
        return *(const unsigned*)(xp + ((pk >> 3) & 0x1FFFF) * L1C + (pk & 7) * 32);
    };

    int i = s;
    for (; i + 7 < en; i += 8) {                       // batch-8: 8 gathers in flight
        int p0 = ldpk(i),     p1 = ldpk(i + 1), p2 = ldpk(i + 2), p3 = ldpk(i + 3);
        int p4 = ldpk(i + 4), p5 = ldpk(i + 5), p6 = ldpk(i + 6), p7 = ldpk(i + 7);
        unsigned v0 = gv(p0), v1 = gv(p1), v2 = gv(p2), v3 = gv(p3);
        unsigned v4 = gv(p4), v5 = gv(p5), v6 = gv(p6), v7 = gv(p7);
        a0 += ((bf2f((short)(v0 & 0xFFFF)) + bf2f((short)(v1 & 0xFFFF)))
             + (bf2f((short)(v2 & 0xFFFF)) + bf2f((short)(v3 & 0xFFFF))))
            + ((bf2f((short)(v4 & 0xFFFF)) + bf2f((short)(v5 & 0xFFFF)))
             + (bf2f((short)(v6 & 0xFFFF)) + bf2f((short)(v7 & 0xFFFF))));
        a1 += ((bf2f((short)(v0 >> 16)) + bf2f((short)(v1 >> 16)))
             + (bf2f((short)(v2 >> 16)) + bf2f((short)(v3 >> 16))))
            + ((bf2f((short)(v4 >> 16)) + bf2f((short)(v5 >> 16)))
             + (bf2f((short)(v6 >> 16)) + bf2f((short)(v7 >> 16))));
    }
    for (; i + 3 < en; i += 4) {
        int p0 = ldpk(i), p1 = ldpk(i + 1), p2 = ldpk(i + 2), p3 = ldpk(i + 3);
        unsigned v0 = gv(p0), v1 = gv(p1), v2 = gv(p2), v3 = gv(p3);
        a0 += (bf2f((short)(v0 & 0xFFFF)) + bf2f((short)(v1 & 0xFFFF)))
            + (bf2f((short)(v2 & 0xFFFF)) + bf2f((short)(v3 & 0xFFFF)));
        a1 += (bf2f((short)(v0 >> 16)) + bf2f((short)(v1 >> 16)))
            + (bf2f((short)(v2 >> 16)) + bf2f((short)(v3 >> 16)));
    }
    for (; i < en; ++i) {
        unsigned v = gv(ldpk(i));
        a0 += bf2f((short)(v & 0xFFFF));
        a1 += bf2f((short)(v >> 16));
    }

    float inv = invl[node];
    unsigned rt = *(const unsigned*)(xw + (row0 + node) * L1C + 256 + l * 2);
    unsigned bc = *(const unsigned*)(smallc + l * 2);
    float o0 = a0 * inv + bf2f((short)(rt & 0xFFFF)) + bf2f((short)(bc & 0xFFFF));
    float o1 = a1 * inv + bf2f((short)(rt >> 16)) + bf2f((short)(bc >> 16));
    o0 = o0 > 0.f ? o0 : 0.f;
    o1 = o1 > 0.f ? o1 : 0.f;
    unsigned w = ((unsigned)(unsigned short)f2bf(o1) << 16) | (unsigned short)f2bf(o0);
    *(unsigned*)(h + (row0 + node) * HID + l * 2) = w;
}

// ---- fused layer-2 (R7, at structural floor): flat batch-8 gather +
// branchless last-wins LDS partial-sum writes (edges rel-sorted per node).
__global__ __launch_bounds__(256) void agg2_fused(const short* __restrict__ h,
                                                  const int* __restrict__ off,
                                                  const int* __restrict__ packed,
                                                  const float* __restrict__ inv_deg,
                                                  const short* __restrict__ w2ct,
                                                  const short* __restrict__ smallc,
                                                  float* __restrict__ out) {
    __shared__ __align__(16) short g2l[16 * G2ST];     // 9.25 KB
    __shared__ int pk_l[PKCAP];                        // 2 KB
    __shared__ float red[4][16][2];
    __shared__ float invl[16];
    int tid = threadIdx.x;
    int row0 = blockIdx.x * 16;                        // NN % 16 == 0
    if (tid < 16) invl[tid] = inv_deg[row0 + tid];
    int st = off[row0];
    int tot = off[row0 + 16] - st;
    // zero the tile (empty (node,rel) cells must be 0) + stage packed
    {
        unsigned* gz = (unsigned*)g2l;
        const int nu = 16 * G2ST / 2;                  // 2368 uints
        for (int j = tid; j < nu; j += 256) gz[j] = 0;
        for (int j = tid; j < tot && j < PKCAP; j += 256) pk_l[j] = packed[st + j];
    }
    __syncthreads();

    int node = tid >> 4, l = tid & 15;                 // 16 lanes/node, 2 dims/lane
    int s = off[row0 + node] - st, en = off[row0 + node + 1] - st;
    float inv = invl[node];
    const short* hp = h + l * 2;
    short* grow = g2l + node * G2ST + l * 2;
    float a0 = 0.f, a1 = 0.f;
    int cur = -1;

    auto ldpk = [&](int j) -> int {
        return (j < PKCAP) ? pk_l[j] : packed[st + j];
    };
    // branchless accumulate + last-wins partial store (v_cndmask, no branch)
    auto acc_edge = [&](int pk, unsigned hv) {
        int rel = pk & 7;
        bool nr = (rel != cur);
        float lo = bf2f((short)(hv & 0xFFFF)) * inv;
        float hi = bf2f((short)(hv >> 16)) * inv;
        a0 = (nr ? 0.f : a0) + lo;
        a1 = (nr ? 0.f : a1) + hi;
        cur = rel;
        unsigned w = ((unsigned)(unsigned short)f2bf(a1) << 16)
                   | (unsigned short)f2bf(a0);
        *(unsigned*)(grow + rel * 32) = w;             // last write per rel wins
    };

    int i = s;
    for (; i + 7 < en; i += 8) {                       // batch-8: 8 gathers in flight
        int p0 = ldpk(i),     p1 = ldpk(i + 1), p2 = ldpk(i + 2), p3 = ldpk(i + 3);
        int p4 = ldpk(i + 4), p5 = ldpk(i + 5), p6 = ldpk(i + 6), p7 = ldpk(i + 7);
        unsigned v0 = *(const unsigned*)(hp + ((p0 >> 3) & 0x1FFFF) * HID);
        unsigned v1 = *(const unsigned*)(hp + ((p1 >> 3) & 0x1FFFF) * HID);
        unsigned v2 = *(const unsigned*)(hp + ((p2 >> 3) & 0x1FFFF) * HID);
        unsigned v3 = *(const unsigned*)(hp + ((p3 >> 3) & 0x1FFFF) * HID);
        unsigned v4 = *(const unsigned*)(hp + ((p4 >> 3) & 0x1FFFF) * HID);
        unsigned v5 = *(const unsigned*)(hp + ((p5 >> 3) & 0x1FFFF) * HID);
        unsigned v6 = *(const unsigned*)(hp + ((p6 >> 3) & 0x1FFFF) * HID);
        unsigned v7 = *(const unsigned*)(hp + ((p7 >> 3) & 0x1FFFF) * HID);
        acc_edge(p0, v0); acc_edge(p1, v1); acc_edge(p2, v2); acc_edge(p3, v3);
        acc_edge(p4, v4); acc_edge(p5, v5); acc_edge(p6, v6); acc_edge(p7, v7);
    }
    for (; i + 3 < en; i += 4) {
        int p0 = ldpk(i), p1 = ldpk(i + 1), p2 = ldpk(i + 2), p3 = ldpk(i + 3);
        unsigned v0 = *(const unsigned*)(hp + ((p0 >> 3) & 0x1FFFF) * HID);
        unsigned v1 = *(const unsigned*)(hp + ((p1 >> 3) & 0x1FFFF) * HID);
        unsigned v2 = *(const unsigned*)(hp + ((p2 >> 3) & 0x1FFFF) * HID);
        unsigned v3 = *(const unsigned*)(hp + ((p3 >> 3) & 0x1FFFF) * HID);
        acc_edge(p0, v0); acc_edge(p1, v1); acc_edge(p2, v2); acc_edge(p3, v3);
    }
    for (; i < en; ++i) {
        int p = ldpk(i);
        unsigned v = *(const unsigned*)(hp + ((p >> 3) & 0x1FFFF) * HID);
        acc_edge(p, v);
    }

    // root cols 256..287 (unscaled h of the node itself)
    *(unsigned*)(grow + 256) = *(const unsigned*)(h + (row0 + node) * HID + l * 2);
    __syncthreads();

    // phase B: 4 waves, wave = 16-col block; MFMA over K=288 from LDS
    int wave = tid >> 6, lane = tid & 63;
    int m15 = lane & 15, quad = lane >> 4;
    const short* wp = w2ct + (wave * 16 + m15) * L2K + quad * 8;
    bf16x8 a[9], b[9];
#pragma unroll
    for (int kt = 0; kt < 9; ++kt) {
        b[kt] = *(const bf16x8*)(wp + kt * 32);
        a[kt] = *(const bf16x8*)(&g2l[m15 * G2ST + quad * 8 + kt * 32]);
    }
    f32x4 acc = {0.f, 0.f, 0.f, 0.f};
#pragma unroll
    for (int kt = 0; kt < 9; ++kt)
        acc = __builtin_amdgcn_mfma_f32_16x16x32_bf16(a[kt], b[kt], acc, 0, 0, 0);

    int c = wave * 16 + m15;
    float lw0 = bf2f(smallc[96 + c * 2 + 0]);
    float lw1 = bf2f(smallc[96 + c * 2 + 1]);
    float b2c = bf2f(smallc[32 + c]);
    float pr0[4], pr1[4];
#pragma unroll
    for (int i2 = 0; i2 < 4; ++i2) {
        float v = acc[i2] + b2c;
        pr0[i2] = v * lw0;
        pr1[i2] = v * lw1;
    }
#pragma unroll
    for (int o = 1; o < 16; o <<= 1) {
#pragma unroll
        for (int i2 = 0; i2 < 4; ++i2) {
            pr0[i2] += __shfl_xor(pr0[i2], o, 64);
            pr1[i2] += __shfl_xor(pr1[i2], o, 64);
        }
    }
    if (m15 == 0) {
#pragma unroll
        for (int i2 = 0; i2 < 4; ++i2) {
            red[wave][quad * 4 + i2][0] = pr0[i2];
            red[wave][quad * 4 + i2][1] = pr1[i2];
        }
    }
    __syncthreads();
    if (tid < 32) {
        int row = tid >> 1, j = tid & 1;
        float v = red[0][row][j] + red[1][row][j] + red[2][row][j] + red[3][row][j]
                + bf2f(smallc[224 + j]);
        out[(row0 + row) * 2 + j] = v;
    }
}

extern "C" void kernel_launch(void* const* d_in, const int* in_sizes, int n_in,
                              void* d_out, int out_size, void* d_ws, size_t ws_size,
                              hipStream_t stream) {
    const void* x     = d_in[0];
    const int*  ei    = (const int*)d_in[1];
    const int*  etype = (const int*)d_in[2];
    const void* W1    = d_in[3];
    const void* root1 = d_in[4];
    const void* b1    = d_in[5];
    const void* W2    = d_in[6];
    const void* root2 = d_in[7];
    const void* b2    = d_in[8];
    const void* lin_w = d_in[9];
    const void* lin_b = d_in[10];
    float* out = (float*)d_out;          // fp32 output (verified round 4)

    const int E = in_sizes[2];          // 1,600,000

    // workspace carve (256B aligned). Peak ~100 MB.
    char* p = (char*)d_ws;
    auto alloc = [&](size_t bytes) { char* r = p; p += (bytes + 255) & ~(size_t)255; return (void*)r; };
    int*   flags   = (int*)  alloc(256);
    int*   off     = (int*)  alloc((size_t)(NN + 1) * 4);
    float* inv_deg = (float*)alloc((size_t)NN * 4);
    int*   packed  = (int*)  alloc((size_t)E * 4);
    int*   cnt     = (int*)  alloc((size_t)NWGS * NCB * 4);
    int*   cbTot   = (int*)  alloc((size_t)NCB * 4);
    int*   seg     = (int*)  alloc((size_t)NCB * NWGS * CCAP * 4);   // 24.6 MB
    short* w1t     = (short*)alloc((size_t)L1C * IN_DIM * 2);
    short* w2ct    = (short*)alloc((size_t)ODIM * L2K * 2);
    short* smallc  = (short*)alloc(256 * 2);
    short* h       = (short*)alloc((size_t)NN * HID * 2);
    short* xw1     = (short*)alloc((size_t)NN * L1C * 2);            // 57.6 MB

    detect<<<1, 1024, 0, stream>>>((const short*)x, (const short*)W1, (const short*)root1,
                                   (const short*)W2, (const short*)root2, (const short*)lin_w,
                                   ei, etype, flags);
    const int prep_items = L1C * IN_DIM + ODIM * L2K + 256;
    prep_all<<<(prep_items + 255) / 256, 256, 0, stream>>>(W1, root1, W2, root2,
                                                           (const short*)b1, (const short*)b2,
                                                           lin_w, (const short*)lin_b,
                                                           w1t, w2ct, smallc, cbTot, flags);

    scatter_coarse<<<NWGS, 1024, 0, stream>>>(ei, etype, cnt, cbTot, seg, E, flags);
    build_cb<<<NCB, 512, 0, stream>>>(cnt, seg, cbTot, off, inv_deg, packed);

    gemm1<<<((NN + 63) / 64 + 3) / 4, 256, 0, stream>>>(x, w1t, xw1, flags);
    agg1<<<NN / 16, 256, 0, stream>>>(xw1, off, packed, inv_deg, smallc, h);
    agg2_fused<<<NN / 16, 256, 0, stream>>>(h, off, packed, inv_deg, w2ct, smallc, out);
}